// Round 5
// baseline (271.644 us; speedup 1.0000x reference)
//
#include <hip/hip_runtime.h>

// GAT layer: N=100000, E=3200000, IN=128, OUT=64.
// R13: deterministic (atomic-free) binning. R11/R12 post-mortem: k_bin's 70us
//   was NOT staging (R12 reg-staging changed nothing) and NOT LDS conflicts
//   (482K cycles total, negligible) -- it was 306K device-scope atomicAdds
//   onto 391 hot words (782 per address, one burst, barrier right after):
//   ~90ns x 782 serialized claims == the observed 70us.
//   Replace claim-by-atomic with radix-style precomputed offsets:
//     k_count:   per-chunk LDS histogram -> histT[bkt][blk]   (no global atomics)
//     k_colscan: per-bucket exclusive scan of chunk counts (+ fixed window base)
//     k_scat:    reg-staged logits + LDS local rank; pos = histT[bkt][blk]+rank
//   Chunk size 2x (8192) also halves chunk-boundary partial-line write RMW.
//   k_linear / k_bucket unchanged (isolate the delta). k_init deleted.

#define IN_DIM 128
#define OUT_DIM 64
#define LNODES 64        // nodes per k_linear block
#define MAXBKT 512       // static sizing; nbkt = ceil(n/256) = 391
#define BKN 256          // nodes per bucket
#define SEPT 8           // edges per thread in count/scatter (1024 thr)
#define SCHUNK (1024 * SEPT)    // 8192 edges per chunk -> nsb = 391
#define CAP 9216         // fixed records per bucket window (mean 8192, sd 90)

// bf16 helpers (manual, round-to-nearest-even; no NaN expected here)
__device__ __forceinline__ unsigned short f2bf(float f) {
    unsigned u = __float_as_uint(f);
    return (unsigned short)((u + 0x7FFFu + ((u >> 16) & 1u)) >> 16);
}
__device__ __forceinline__ float bf2f(unsigned short u) {
    return __uint_as_float((unsigned)u << 16);
}

// guarded exp for online-softmax merges: maps NaN (from -inf - -inf) to ~0
__device__ __forceinline__ float expg(float d) {
    return __expf(fmaxf(d, -80.f));
}

// ---------------- K1: h = x@W (bf16 out), hs = h.a_src, ht = h.a_tgt --------
// 512 threads: lane16 = tid&15 -> 4 dims (float4), mrow = tid>>4 in [0,32)
// -> nodes mrow, mrow+32. W and x-tile staged in LDS. (R4-proven structure.)
__global__ __launch_bounds__(512) void k_linear(
    const float* __restrict__ x, const float* __restrict__ W,
    const float* __restrict__ a_src, const float* __restrict__ a_tgt,
    unsigned short* __restrict__ hh, float* __restrict__ hs,
    float* __restrict__ ht, int n)
{
    __shared__ float ws_W[IN_DIM][OUT_DIM];        // 32 KB, original [k][dim]
    __shared__ float xs[LNODES][IN_DIM + 4];       // padded rows: 33 KB
    const int tid   = threadIdx.x;
    const int node0 = blockIdx.x * LNODES;

    {
        const float4* Wsrc = (const float4*)W;
        float4* Wdst = (float4*)&ws_W[0][0];
        #pragma unroll
        for (int i = 0; i < 4; ++i) Wdst[tid + 512 * i] = Wsrc[tid + 512 * i];
    }
    {
        int nrows = n - node0; if (nrows > LNODES) nrows = LNODES;
        for (int i = tid; i < nrows * 32; i += 512) {
            int r = i >> 5, c4 = i & 31;
            float4 v = ((const float4*)(x + (size_t)(node0 + r) * IN_DIM))[c4];
            *(float4*)&xs[r][c4 * 4] = v;
        }
    }
    __syncthreads();

    const int lane16 = tid & 15;
    const int mrow   = tid >> 4;
    float4 acc[2];
    acc[0] = make_float4(0.f, 0.f, 0.f, 0.f);
    acc[1] = make_float4(0.f, 0.f, 0.f, 0.f);

    #pragma unroll 2
    for (int k = 0; k < IN_DIM; k += 4) {
        float4 w0 = *(const float4*)&ws_W[k + 0][lane16 * 4];
        float4 w1 = *(const float4*)&ws_W[k + 1][lane16 * 4];
        float4 w2 = *(const float4*)&ws_W[k + 2][lane16 * 4];
        float4 w3 = *(const float4*)&ws_W[k + 3][lane16 * 4];
        #pragma unroll
        for (int u = 0; u < 2; ++u) {
            float4 xv = *(const float4*)&xs[mrow + 32 * u][k];
            acc[u].x += w0.x * xv.x + w1.x * xv.y + w2.x * xv.z + w3.x * xv.w;
            acc[u].y += w0.y * xv.x + w1.y * xv.y + w2.y * xv.z + w3.y * xv.w;
            acc[u].z += w0.z * xv.x + w1.z * xv.y + w2.z * xv.z + w3.z * xv.w;
            acc[u].w += w0.w * xv.x + w1.w * xv.y + w2.w * xv.z + w3.w * xv.w;
        }
    }

    const float4 as = ((const float4*)a_src)[lane16];
    const float4 at = ((const float4*)a_tgt)[lane16];
    #pragma unroll
    for (int u = 0; u < 2; ++u) {
        int node = node0 + mrow + 32 * u;
        float ps = acc[u].x * as.x + acc[u].y * as.y + acc[u].z * as.z + acc[u].w * as.w;
        float pt = acc[u].x * at.x + acc[u].y * at.y + acc[u].z * at.z + acc[u].w * at.w;
        #pragma unroll
        for (int off = 8; off; off >>= 1) {
            ps += __shfl_xor(ps, off);
            pt += __shfl_xor(pt, off);
        }
        if (node < n) {
            ushort4 hv;
            hv.x = f2bf(acc[u].x); hv.y = f2bf(acc[u].y);
            hv.z = f2bf(acc[u].z); hv.w = f2bf(acc[u].w);
            ((ushort4*)(hh + (size_t)node * OUT_DIM))[lane16] = hv;
            if (lane16 == 0) { hs[node] = ps; ht[node] = pt; }
        }
    }
}

// ---------------- K2: per-chunk bucket histogram ----------------------------
// One block per 8192-edge chunk: LDS 391-counter histogram of tgt>>8, then
// write column histT[bkt*nsb + blk]. No global atomics anywhere.
__global__ __launch_bounds__(1024) void k_count(
    const int* __restrict__ tgt, int* __restrict__ histT,
    int ecount, int nbkt, int nsb)
{
    __shared__ int h[MAXBKT];
    const int tid = threadIdx.x;
    const int e0  = blockIdx.x * SCHUNK;
    for (int i = tid; i < nbkt; i += 1024) h[i] = 0;
    __syncthreads();
    #pragma unroll
    for (int k = 0; k < SEPT; ++k) {
        int j = e0 + k * 1024 + tid;
        if (j < ecount) atomicAdd(&h[tgt[j] >> 8], 1);
    }
    __syncthreads();
    for (int i = tid; i < nbkt; i += 1024) histT[i * nsb + blockIdx.x] = h[i];
}

// ---------------- K3: per-bucket exclusive scan of chunk counts -------------
// One block per bucket. In-place: histT[bkt][blk] becomes the absolute write
// base (bkt*CAP + exclusive prefix). bfill[bkt] = window end (for k_bucket).
__global__ __launch_bounds__(512) void k_colscan(
    int* __restrict__ histT, int* __restrict__ bfill, int nsb)
{
    __shared__ int lds[512];
    const int bkt = blockIdx.x;
    const int tid = threadIdx.x;
    int v = (tid < nsb) ? histT[bkt * nsb + tid] : 0;
    lds[tid] = v;
    __syncthreads();
    for (int off = 1; off < 512; off <<= 1) {
        int u = (tid >= off) ? lds[tid - off] : 0;
        __syncthreads();
        lds[tid] += u;
        __syncthreads();
    }
    int excl = lds[tid] - v;
    if (tid < nsb) histT[bkt * nsb + tid] = bkt * CAP + excl;
    if (tid == 511) bfill[bkt] = bkt * CAP + lds[511];
}

// ---------------- K4: edge logits + deterministic scatter -------------------
// Register-staged (R12): coalesced edge loads, all hs/ht gathers in flight,
// LDS-atomic LOCAL rank (proven negligible), then pos = histT[bkt][blk]+rank.
// Zero global atomics; chunk writes are block-owned -> XCD-local assembly.
// Record: (u32 key = (src<<8)|(t&255), float v). src<2^17 -> key fits 25 bits.
__global__ __launch_bounds__(1024) void k_scat(
    const int* __restrict__ src, const int* __restrict__ tgt,
    const float* __restrict__ ew, const float* __restrict__ hs,
    const float* __restrict__ ht, const int* __restrict__ histT,
    float2* __restrict__ ecoarse, int ecount, int nbkt, int nsb)
{
    __shared__ int h[MAXBKT];             // local rank counters
    __shared__ int base[MAXBKT];          // this block's write bases
    const int tid = threadIdx.x;
    const int e0  = blockIdx.x * SCHUNK;

    for (int i = tid; i < nbkt; i += 1024) {
        h[i] = 0;
        base[i] = histT[i * nsb + blockIdx.x];
    }

    // 1) coalesced edge loads; key/bucket packed immediately
    unsigned kreg[SEPT]; int breg[SEPT]; float wreg[SEPT];
    #pragma unroll
    for (int k = 0; k < SEPT; ++k) {
        int j = e0 + k * 1024 + tid;
        bool valid = j < ecount;
        int s = valid ? src[j] : 0;
        int t = valid ? tgt[j] : 0;
        wreg[k] = valid ? ew[j] : 0.f;
        kreg[k] = ((unsigned)s << 8) | ((unsigned)t & 255u);
        breg[k] = t >> 8;
    }
    // 2) all gathers independent and in flight together
    float hsr[SEPT], htr[SEPT];
    #pragma unroll
    for (int k = 0; k < SEPT; ++k) hsr[k] = hs[kreg[k] >> 8];
    #pragma unroll
    for (int k = 0; k < SEPT; ++k) htr[k] = ht[(breg[k] << 8) | (int)(kreg[k] & 255u)];

    __syncthreads();   // h[] zeroed, base[] loaded

    // 3) local rank within (block,bucket)
    int rank[SEPT];
    #pragma unroll
    for (int k = 0; k < SEPT; ++k) {
        int j = e0 + k * 1024 + tid;
        if (j < ecount) rank[k] = atomicAdd(&h[breg[k]], 1);
    }

    // 4) write records straight from registers (deterministic positions)
    #pragma unroll
    for (int k = 0; k < SEPT; ++k) {
        int j = e0 + k * 1024 + tid;
        if (j < ecount) {
            float v = hsr[k] + htr[k];
            v = (v > 0.f) ? v : 0.2f * v;      // leaky_relu slope 0.2
            v *= wreg[k];
            ecoarse[base[breg[k]] + rank[k]] = make_float2(__uint_as_float(kreg[k]), v);
        }
    }
}

// ---------------- K5: per-bucket sort(LDS) + softmax + aggregation ----------
// One 1024-thread block per bucket. Pass 1: 256-counter LDS histogram over the
// bucket window (coalesced). LDS scan -> segment starts. Pass 2: re-read
// (L2-hot) and scatter node-sorted into LDS recs. Phase A: per-node online
// softmax, 16-lane groups (4 nodes/wave). Phase B: proven wave-per-node
// register aggregation, edges from LDS, hh gathered from global.
// LDS: 72KB recs + ~5KB aux -> 2 blocks/CU = 32 waves/CU.
__global__ __launch_bounds__(1024, 8) void k_bucket(
    const int* __restrict__ bfill, const float2* __restrict__ ecoarse,
    const unsigned short* __restrict__ hh, float* __restrict__ out, int n)
{
    __shared__ float2 recs[CAP];       // 73728 B
    __shared__ int   cnt[BKN];
    __shared__ int   pos0[BKN];        // segment starts
    __shared__ int   fill[BKN];        // scatter cursors
    __shared__ float mf[BKN];
    __shared__ float rden[BKN];

    const int tid   = threadIdx.x;
    const int bkt   = blockIdx.x;
    const int base  = bkt * CAP;
    const int node0 = bkt << 8;
    const int mcnt  = bfill[bkt] - base;   // edges in this bucket

    for (int i = tid; i < BKN; i += 1024) cnt[i] = 0;
    __syncthreads();

    // Pass 1: histogram (coalesced window read)
    for (int j = tid; j < mcnt; j += 1024) {
        unsigned k = __float_as_uint(ecoarse[base + j].x);
        atomicAdd(&cnt[k & 255u], 1);
    }
    __syncthreads();

    // Exclusive scan of 256 counters (Hillis-Steele on first 256 threads)
    if (tid < BKN) pos0[tid] = cnt[tid];
    __syncthreads();
    for (int off = 1; off < BKN; off <<= 1) {
        int u = 0;
        if (tid < BKN && tid >= off) u = pos0[tid - off];
        __syncthreads();
        if (tid < BKN) pos0[tid] += u;
        __syncthreads();
    }
    if (tid < BKN) fill[tid] = pos0[tid] - cnt[tid];   // exclusive
    __syncthreads();
    if (tid < BKN) pos0[tid] = fill[tid];              // stable segment starts
    __syncthreads();

    // Pass 2: scatter node-sorted into LDS (window re-read is L2-hot)
    for (int j = tid; j < mcnt; j += 1024) {
        float2 e = ecoarse[base + j];
        unsigned k = __float_as_uint(e.x);
        int p = atomicAdd(&fill[k & 255u], 1);
        recs[p] = e;
    }
    __syncthreads();

    // Phase A: per-node online softmax; 16-lane groups, 4 nodes per wave
    {
        const int G   = tid >> 4;      // 0..63
        const int l16 = tid & 15;
        #pragma unroll
        for (int r = 0; r < 4; ++r) {
            int tl = G + 64 * r;
            int s0 = pos0[tl], c = cnt[tl];
            float m = -INFINITY, s = 0.f;
            for (int j = l16; j < c; j += 16) {
                float v = recs[s0 + j].y;
                float nm = fmaxf(m, v);
                s = s * expg(m - nm) + expg(v - nm);
                m = nm;
            }
            #pragma unroll
            for (int off = 8; off; off >>= 1) {
                float mo = __shfl_xor(m, off);
                float so = __shfl_xor(s, off);
                float nm = fmaxf(m, mo);
                s = s * expg(m - nm) + so * expg(mo - nm);
                m = nm;
            }
            if (l16 == 0) { mf[tl] = m; rden[tl] = 1.f / (s + 1e-10f); }
        }
    }
    __syncthreads();

    // Phase B: wave per node, register aggregation; edges from LDS
    const int lane = tid & 63;
    const int wv   = tid >> 6;       // 0..15
    const int g    = lane >> 4;      // group 0..3 -> edge j+g
    const int l4   = lane & 15;      // 4 dims per lane
    #pragma unroll 1
    for (int r = 0; r < 16; ++r) {
        int tl = wv + 16 * r;
        int node = node0 + tl;
        if (node >= n) continue;
        int s0 = pos0[tl], e_ = s0 + cnt[tl];
        float m = mf[tl], rd = rden[tl];
        float4 a0 = make_float4(0.f, 0.f, 0.f, 0.f);
        float4 a1 = make_float4(0.f, 0.f, 0.f, 0.f);
        int j = s0;
        for (; j + 8 <= e_; j += 8) {
            float2 e0 = recs[j + g];
            float2 e1 = recs[j + 4 + g];
            int sA = (int)(__float_as_uint(e0.x) >> 8);
            int sB = (int)(__float_as_uint(e1.x) >> 8);
            ushort4 u0 = ((const ushort4*)(hh + (size_t)sA * OUT_DIM))[l4];
            ushort4 u1 = ((const ushort4*)(hh + (size_t)sB * OUT_DIM))[l4];
            float c0 = __expf(e0.y - m) * rd;
            float c1 = __expf(e1.y - m) * rd;
            a0.x += c0 * bf2f(u0.x); a0.y += c0 * bf2f(u0.y);
            a0.z += c0 * bf2f(u0.z); a0.w += c0 * bf2f(u0.w);
            a1.x += c1 * bf2f(u1.x); a1.y += c1 * bf2f(u1.y);
            a1.z += c1 * bf2f(u1.z); a1.w += c1 * bf2f(u1.w);
        }
        for (; j < e_; j += 4) {
            int jj = j + g;
            bool valid = jj < e_;
            float2 ed = recs[valid ? jj : (e_ - 1)];
            int sidx = (int)(__float_as_uint(ed.x) >> 8);
            ushort4 uv = ((const ushort4*)(hh + (size_t)sidx * OUT_DIM))[l4];
            float c = valid ? __expf(ed.y - m) * rd : 0.f;
            a0.x += c * bf2f(uv.x); a0.y += c * bf2f(uv.y);
            a0.z += c * bf2f(uv.z); a0.w += c * bf2f(uv.w);
        }
        a0.x += a1.x; a0.y += a1.y; a0.z += a1.z; a0.w += a1.w;

        #pragma unroll
        for (int off = 32; off >= 16; off >>= 1) {
            a0.x += __shfl_xor(a0.x, off);
            a0.y += __shfl_xor(a0.y, off);
            a0.z += __shfl_xor(a0.z, off);
            a0.w += __shfl_xor(a0.w, off);
        }
        if (g == 0)
            ((float4*)(out + (size_t)node * OUT_DIM))[l4] = a0;
    }
}

extern "C" void kernel_launch(void* const* d_in, const int* in_sizes, int n_in,
                              void* d_out, int out_size, void* d_ws, size_t ws_size,
                              hipStream_t stream) {
    const float* x     = (const float*)d_in[0];
    const int*   eidx  = (const int*)d_in[1];
    const float* ew    = (const float*)d_in[2];
    const float* W     = (const float*)d_in[3];
    const float* a_src = (const float*)d_in[4];
    const float* a_tgt = (const float*)d_in[5];
    float* out = (float*)d_out;

    const int n = in_sizes[0] / IN_DIM;     // 100000
    const int E = in_sizes[2];              // 3200000
    const int* src = eidx;
    const int* tgt = eidx + E;
    const int nbkt = (n + BKN - 1) / BKN;        // 391 <= MAXBKT
    const int nsb  = (E + SCHUNK - 1) / SCHUNK;  // 391 <= 512

    // Workspace layout (4-byte units).
    // hh 12.8 + hs/ht 0.8 + bfill + histT 0.61 + windows 28.8 ~= 43.1 MB.
    unsigned* ws = (unsigned*)d_ws;
    unsigned short* hh = (unsigned short*)ws;  ws += (size_t)n * OUT_DIM / 2;
    float* hs     = (float*)ws;          ws += n;
    float* ht     = (float*)ws;          ws += n;
    int*   bfill  = (int*)ws;            ws += MAXBKT;
    int*   histT  = (int*)ws;            ws += (size_t)nbkt * nsb;
    ws = (unsigned*)(((uintptr_t)ws + 7) & ~(uintptr_t)7);
    float2* ecoarse = (float2*)ws;       // nbkt * CAP records (fixed windows)

    k_linear<<<(n + LNODES - 1) / LNODES, 512, 0, stream>>>(x, W, a_src, a_tgt, hh, hs, ht, n);
    k_count<<<nsb, 1024, 0, stream>>>(tgt, histT, E, nbkt, nsb);
    k_colscan<<<nbkt, 512, 0, stream>>>(histT, bfill, nsb);
    k_scat<<<nsb, 1024, 0, stream>>>(src, tgt, ew, hs, ht, histT, ecoarse, E, nbkt, nsb);
    k_bucket<<<nbkt, 1024, 0, stream>>>(bfill, ecoarse, hh, out, n);
}

// Round 6
// 271.314 us; speedup vs baseline: 1.0012x; 1.0012x over previous
//
#include <hip/hip_runtime.h>

// GAT layer: N=100000, E=3200000, IN=128, OUT=64.
// R14: MFMA k_linear. Ledger across R10-R13 pins the invisible k_linear at
//   ~110us: 192 ds_read_b128/thread for 1024 scalar FMAs = DS-pipe-bound
//   (~12cyc/b128, m134). Replace with 16x16x32 bf16 MFMA GEMM, split-bf16
//   (hi+lo) for f32-equivalent accuracy (err ~2^-17; absmax must stay
//   0.0078125): 3 products hi*hi + hi*lo + lo*hi. 64-row blocks, 4 waves,
//   LDS x/W^T tiles padded to 136 elems (272B rows: 16B-aligned, ~2-way
//   bank aliasing = free). hs/ht via in-register dot + width-16 shfl;
//   hh repacked through LDS for coalesced ushort4 stores.
//   k_count / k_colscan / k_scat / k_bucket byte-identical to R13.

#define IN_DIM 128
#define OUT_DIM 64
#define MAXBKT 512       // static sizing; nbkt = ceil(n/256) = 391
#define BKN 256          // nodes per bucket
#define SEPT 8           // edges per thread in count/scatter (1024 thr)
#define SCHUNK (1024 * SEPT)    // 8192 edges per chunk -> nsb = 391
#define CAP 9216         // fixed records per bucket window (mean 8192, sd 90)

typedef __attribute__((ext_vector_type(8))) short bf16x8;
typedef __attribute__((ext_vector_type(4))) float f32x4;

// bf16 helpers (manual, round-to-nearest-even; no NaN expected here)
__device__ __forceinline__ unsigned short f2bf(float f) {
    unsigned u = __float_as_uint(f);
    return (unsigned short)((u + 0x7FFFu + ((u >> 16) & 1u)) >> 16);
}
__device__ __forceinline__ float bf2f(unsigned short u) {
    return __uint_as_float((unsigned)u << 16);
}

// guarded exp for online-softmax merges: maps NaN (from -inf - -inf) to ~0
__device__ __forceinline__ float expg(float d) {
    return __expf(fmaxf(d, -80.f));
}

// ---------------- K1: h = x@W via MFMA (split bf16), hs/ht epilogue --------
// One 256-thread block per 64 nodes. LDS tiles (padded stride 136):
//   xhi/xlo[64][136]  : x rows, split bf16
//   whi/wlo[64][136]  : W^T (dim-major), split bf16
// Wave wv owns rows [wv*16, wv*16+16). A-frag: row=l&15, k=(l>>4)*8+j.
// B-frag: col=l&15 (dim), k=(l>>4)*8+j. C/D: col=l&15, row=(l>>4)*4+reg
// (verified layout, learn_hip m89). 4 nt-tiles x 4 k0 x 3 split products.
__global__ __launch_bounds__(256) void k_linear(
    const float* __restrict__ x, const float* __restrict__ W,
    const float* __restrict__ a_src, const float* __restrict__ a_tgt,
    unsigned short* __restrict__ hh, float* __restrict__ hs,
    float* __restrict__ ht, int n)
{
    __shared__ unsigned short xhi[64][136];   // 17408 B each, 69632 total
    __shared__ unsigned short xlo[64][136];
    __shared__ unsigned short whi[64][136];   // [dim][k]
    __shared__ unsigned short wlo[64][136];
    const int tid   = threadIdx.x;
    const int node0 = blockIdx.x * 64;

    // Stage W transposed+split: W[k][d] (row-major 128x64) -> w*[d][k].
    // 2048 float4 / 256 thr = 8 per thread, coalesced.
    {
        const float4* W4 = (const float4*)W;
        #pragma unroll
        for (int j = 0; j < 8; ++j) {
            int i4 = tid + 256 * j;
            int k = i4 >> 4, d4 = i4 & 15;
            float4 v = W4[i4];
            float vv[4] = {v.x, v.y, v.z, v.w};
            #pragma unroll
            for (int m = 0; m < 4; ++m) {
                unsigned short hi = f2bf(vv[m]);
                float lo = vv[m] - bf2f(hi);
                whi[d4 * 4 + m][k] = hi;
                wlo[d4 * 4 + m][k] = f2bf(lo);
            }
        }
    }
    // Stage x split: 64 rows x 128 cols, 2048 float4, coalesced; zero-pad.
    {
        #pragma unroll
        for (int j = 0; j < 8; ++j) {
            int i4 = tid + 256 * j;
            int r = i4 >> 5, c4 = i4 & 31;
            int node = node0 + r;
            float4 v = make_float4(0.f, 0.f, 0.f, 0.f);
            if (node < n) v = ((const float4*)(x + (size_t)node * IN_DIM))[c4];
            float vv[4] = {v.x, v.y, v.z, v.w};
            ushort4 ph, pl;
            unsigned short* php = (unsigned short*)&ph;
            unsigned short* plp = (unsigned short*)&pl;
            #pragma unroll
            for (int m = 0; m < 4; ++m) {
                unsigned short hi = f2bf(vv[m]);
                php[m] = hi;
                plp[m] = f2bf(vv[m] - bf2f(hi));
            }
            *(ushort4*)&xhi[r][c4 * 4] = ph;
            *(ushort4*)&xlo[r][c4 * 4] = pl;
        }
    }
    __syncthreads();

    const int l15  = tid & 15;          // lane&15
    const int lhi  = (tid & 63) >> 4;   // lane>>4, 0..3
    const int wv   = tid >> 6;          // wave 0..3
    const int arow = wv * 16 + l15;     // A row within block
    const int kb   = lhi * 8;           // k sub-offset

    // A fragments (registers): 4 k0-steps x {hi,lo}
    bf16x8 ahi[4], alo[4];
    #pragma unroll
    for (int k0 = 0; k0 < 4; ++k0) {
        ahi[k0] = *(const bf16x8*)&xhi[arow][k0 * 32 + kb];
        alo[k0] = *(const bf16x8*)&xlo[arow][k0 * 32 + kb];
    }

    f32x4 acc[4];
    #pragma unroll
    for (int ntt = 0; ntt < 4; ++ntt) acc[ntt] = (f32x4){0.f, 0.f, 0.f, 0.f};

    #pragma unroll
    for (int ntt = 0; ntt < 4; ++ntt) {
        #pragma unroll
        for (int k0 = 0; k0 < 4; ++k0) {
            bf16x8 bhi = *(const bf16x8*)&whi[ntt * 16 + l15][k0 * 32 + kb];
            bf16x8 blo = *(const bf16x8*)&wlo[ntt * 16 + l15][k0 * 32 + kb];
            acc[ntt] = __builtin_amdgcn_mfma_f32_16x16x32_bf16(ahi[k0], bhi, acc[ntt], 0, 0, 0);
            acc[ntt] = __builtin_amdgcn_mfma_f32_16x16x32_bf16(ahi[k0], blo, acc[ntt], 0, 0, 0);
            acc[ntt] = __builtin_amdgcn_mfma_f32_16x16x32_bf16(alo[k0], bhi, acc[ntt], 0, 0, 0);
        }
    }

    // hs/ht epilogue: row R = lhi*4 + q held by the 16 lanes sharing lhi.
    float asv[4], atv[4];
    #pragma unroll
    for (int ntt = 0; ntt < 4; ++ntt) {
        asv[ntt] = a_src[ntt * 16 + l15];
        atv[ntt] = a_tgt[ntt * 16 + l15];
    }
    #pragma unroll
    for (int q = 0; q < 4; ++q) {
        float ps = 0.f, pt = 0.f;
        #pragma unroll
        for (int ntt = 0; ntt < 4; ++ntt) {
            ps += acc[ntt][q] * asv[ntt];
            pt += acc[ntt][q] * atv[ntt];
        }
        #pragma unroll
        for (int off = 8; off; off >>= 1) {
            ps += __shfl_xor(ps, off);
            pt += __shfl_xor(pt, off);
        }
        int node = node0 + wv * 16 + lhi * 4 + q;
        if (l15 == 0 && node < n) { hs[node] = ps; ht[node] = pt; }
    }

    // hh: repack through LDS (xhi reusable: A-frags already in registers
    // block-wide once every wave passed the barrier below) -> coalesced.
    __syncthreads();
    #pragma unroll
    for (int ntt = 0; ntt < 4; ++ntt) {
        #pragma unroll
        for (int q = 0; q < 4; ++q) {
            xhi[wv * 16 + lhi * 4 + q][ntt * 16 + l15] = f2bf(acc[ntt][q]);
        }
    }
    __syncthreads();
    #pragma unroll
    for (int j = 0; j < 4; ++j) {
        int i = tid + 256 * j;          // 1024 ushort4 = 64 rows x 16
        int r = i >> 4, c4 = i & 15;
        int node = node0 + r;
        if (node < n) {
            ushort4 v = *(const ushort4*)&xhi[r][c4 * 4];
            ((ushort4*)(hh + (size_t)node * OUT_DIM))[c4] = v;
        }
    }
}

// ---------------- K2: per-chunk bucket histogram ----------------------------
// One block per 8192-edge chunk: LDS 391-counter histogram of tgt>>8, then
// write column histT[bkt*nsb + blk]. No global atomics anywhere.
__global__ __launch_bounds__(1024) void k_count(
    const int* __restrict__ tgt, int* __restrict__ histT,
    int ecount, int nbkt, int nsb)
{
    __shared__ int h[MAXBKT];
    const int tid = threadIdx.x;
    const int e0  = blockIdx.x * SCHUNK;
    for (int i = tid; i < nbkt; i += 1024) h[i] = 0;
    __syncthreads();
    #pragma unroll
    for (int k = 0; k < SEPT; ++k) {
        int j = e0 + k * 1024 + tid;
        if (j < ecount) atomicAdd(&h[tgt[j] >> 8], 1);
    }
    __syncthreads();
    for (int i = tid; i < nbkt; i += 1024) histT[i * nsb + blockIdx.x] = h[i];
}

// ---------------- K3: per-bucket exclusive scan of chunk counts -------------
// One block per bucket. In-place: histT[bkt][blk] becomes the absolute write
// base (bkt*CAP + exclusive prefix). bfill[bkt] = window end (for k_bucket).
__global__ __launch_bounds__(512) void k_colscan(
    int* __restrict__ histT, int* __restrict__ bfill, int nsb)
{
    __shared__ int lds[512];
    const int bkt = blockIdx.x;
    const int tid = threadIdx.x;
    int v = (tid < nsb) ? histT[bkt * nsb + tid] : 0;
    lds[tid] = v;
    __syncthreads();
    for (int off = 1; off < 512; off <<= 1) {
        int u = (tid >= off) ? lds[tid - off] : 0;
        __syncthreads();
        lds[tid] += u;
        __syncthreads();
    }
    int excl = lds[tid] - v;
    if (tid < nsb) histT[bkt * nsb + tid] = bkt * CAP + excl;
    if (tid == 511) bfill[bkt] = bkt * CAP + lds[511];
}

// ---------------- K4: edge logits + deterministic scatter -------------------
// Register-staged: coalesced edge loads, all hs/ht gathers in flight,
// LDS-atomic LOCAL rank, then pos = histT[bkt][blk]+rank.
// Zero global atomics; chunk writes are block-owned -> XCD-local assembly.
// Record: (u32 key = (src<<8)|(t&255), float v). src<2^17 -> key fits 25 bits.
__global__ __launch_bounds__(1024) void k_scat(
    const int* __restrict__ src, const int* __restrict__ tgt,
    const float* __restrict__ ew, const float* __restrict__ hs,
    const float* __restrict__ ht, const int* __restrict__ histT,
    float2* __restrict__ ecoarse, int ecount, int nbkt, int nsb)
{
    __shared__ int h[MAXBKT];             // local rank counters
    __shared__ int base[MAXBKT];          // this block's write bases
    const int tid = threadIdx.x;
    const int e0  = blockIdx.x * SCHUNK;

    for (int i = tid; i < nbkt; i += 1024) {
        h[i] = 0;
        base[i] = histT[i * nsb + blockIdx.x];
    }

    // 1) coalesced edge loads; key/bucket packed immediately
    unsigned kreg[SEPT]; int breg[SEPT]; float wreg[SEPT];
    #pragma unroll
    for (int k = 0; k < SEPT; ++k) {
        int j = e0 + k * 1024 + tid;
        bool valid = j < ecount;
        int s = valid ? src[j] : 0;
        int t = valid ? tgt[j] : 0;
        wreg[k] = valid ? ew[j] : 0.f;
        kreg[k] = ((unsigned)s << 8) | ((unsigned)t & 255u);
        breg[k] = t >> 8;
    }
    // 2) all gathers independent and in flight together
    float hsr[SEPT], htr[SEPT];
    #pragma unroll
    for (int k = 0; k < SEPT; ++k) hsr[k] = hs[kreg[k] >> 8];
    #pragma unroll
    for (int k = 0; k < SEPT; ++k) htr[k] = ht[(breg[k] << 8) | (int)(kreg[k] & 255u)];

    __syncthreads();   // h[] zeroed, base[] loaded

    // 3) local rank within (block,bucket)
    int rank[SEPT];
    #pragma unroll
    for (int k = 0; k < SEPT; ++k) {
        int j = e0 + k * 1024 + tid;
        if (j < ecount) rank[k] = atomicAdd(&h[breg[k]], 1);
    }

    // 4) write records straight from registers (deterministic positions)
    #pragma unroll
    for (int k = 0; k < SEPT; ++k) {
        int j = e0 + k * 1024 + tid;
        if (j < ecount) {
            float v = hsr[k] + htr[k];
            v = (v > 0.f) ? v : 0.2f * v;      // leaky_relu slope 0.2
            v *= wreg[k];
            ecoarse[base[breg[k]] + rank[k]] = make_float2(__uint_as_float(kreg[k]), v);
        }
    }
}

// ---------------- K5: per-bucket sort(LDS) + softmax + aggregation ----------
// One 1024-thread block per bucket. Pass 1: 256-counter LDS histogram over the
// bucket window (coalesced). LDS scan -> segment starts. Pass 2: re-read
// (L2-hot) and scatter node-sorted into LDS recs. Phase A: per-node online
// softmax, 16-lane groups (4 nodes/wave). Phase B: proven wave-per-node
// register aggregation, edges from LDS, hh gathered from global.
__global__ __launch_bounds__(1024, 8) void k_bucket(
    const int* __restrict__ bfill, const float2* __restrict__ ecoarse,
    const unsigned short* __restrict__ hh, float* __restrict__ out, int n)
{
    __shared__ float2 recs[CAP];       // 73728 B
    __shared__ int   cnt[BKN];
    __shared__ int   pos0[BKN];        // segment starts
    __shared__ int   fill[BKN];        // scatter cursors
    __shared__ float mf[BKN];
    __shared__ float rden[BKN];

    const int tid   = threadIdx.x;
    const int bkt   = blockIdx.x;
    const int base  = bkt * CAP;
    const int node0 = bkt << 8;
    const int mcnt  = bfill[bkt] - base;   // edges in this bucket

    for (int i = tid; i < BKN; i += 1024) cnt[i] = 0;
    __syncthreads();

    // Pass 1: histogram (coalesced window read)
    for (int j = tid; j < mcnt; j += 1024) {
        unsigned k = __float_as_uint(ecoarse[base + j].x);
        atomicAdd(&cnt[k & 255u], 1);
    }
    __syncthreads();

    // Exclusive scan of 256 counters (Hillis-Steele on first 256 threads)
    if (tid < BKN) pos0[tid] = cnt[tid];
    __syncthreads();
    for (int off = 1; off < BKN; off <<= 1) {
        int u = 0;
        if (tid < BKN && tid >= off) u = pos0[tid - off];
        __syncthreads();
        if (tid < BKN) pos0[tid] += u;
        __syncthreads();
    }
    if (tid < BKN) fill[tid] = pos0[tid] - cnt[tid];   // exclusive
    __syncthreads();
    if (tid < BKN) pos0[tid] = fill[tid];              // stable segment starts
    __syncthreads();

    // Pass 2: scatter node-sorted into LDS (window re-read is L2-hot)
    for (int j = tid; j < mcnt; j += 1024) {
        float2 e = ecoarse[base + j];
        unsigned k = __float_as_uint(e.x);
        int p = atomicAdd(&fill[k & 255u], 1);
        recs[p] = e;
    }
    __syncthreads();

    // Phase A: per-node online softmax; 16-lane groups, 4 nodes per wave
    {
        const int G   = tid >> 4;      // 0..63
        const int l16 = tid & 15;
        #pragma unroll
        for (int r = 0; r < 4; ++r) {
            int tl = G + 64 * r;
            int s0 = pos0[tl], c = cnt[tl];
            float m = -INFINITY, s = 0.f;
            for (int j = l16; j < c; j += 16) {
                float v = recs[s0 + j].y;
                float nm = fmaxf(m, v);
                s = s * expg(m - nm) + expg(v - nm);
                m = nm;
            }
            #pragma unroll
            for (int off = 8; off; off >>= 1) {
                float mo = __shfl_xor(m, off);
                float so = __shfl_xor(s, off);
                float nm = fmaxf(m, mo);
                s = s * expg(m - nm) + so * expg(mo - nm);
                m = nm;
            }
            if (l16 == 0) { mf[tl] = m; rden[tl] = 1.f / (s + 1e-10f); }
        }
    }
    __syncthreads();

    // Phase B: wave per node, register aggregation; edges from LDS
    const int lane = tid & 63;
    const int wv   = tid >> 6;       // 0..15
    const int g    = lane >> 4;      // group 0..3 -> edge j+g
    const int l4   = lane & 15;      // 4 dims per lane
    #pragma unroll 1
    for (int r = 0; r < 16; ++r) {
        int tl = wv + 16 * r;
        int node = node0 + tl;
        if (node >= n) continue;
        int s0 = pos0[tl], e_ = s0 + cnt[tl];
        float m = mf[tl], rd = rden[tl];
        float4 a0 = make_float4(0.f, 0.f, 0.f, 0.f);
        float4 a1 = make_float4(0.f, 0.f, 0.f, 0.f);
        int j = s0;
        for (; j + 8 <= e_; j += 8) {
            float2 e0 = recs[j + g];
            float2 e1 = recs[j + 4 + g];
            int sA = (int)(__float_as_uint(e0.x) >> 8);
            int sB = (int)(__float_as_uint(e1.x) >> 8);
            ushort4 u0 = ((const ushort4*)(hh + (size_t)sA * OUT_DIM))[l4];
            ushort4 u1 = ((const ushort4*)(hh + (size_t)sB * OUT_DIM))[l4];
            float c0 = __expf(e0.y - m) * rd;
            float c1 = __expf(e1.y - m) * rd;
            a0.x += c0 * bf2f(u0.x); a0.y += c0 * bf2f(u0.y);
            a0.z += c0 * bf2f(u0.z); a0.w += c0 * bf2f(u0.w);
            a1.x += c1 * bf2f(u1.x); a1.y += c1 * bf2f(u1.y);
            a1.z += c1 * bf2f(u1.z); a1.w += c1 * bf2f(u1.w);
        }
        for (; j < e_; j += 4) {
            int jj = j + g;
            bool valid = jj < e_;
            float2 ed = recs[valid ? jj : (e_ - 1)];
            int sidx = (int)(__float_as_uint(ed.x) >> 8);
            ushort4 uv = ((const ushort4*)(hh + (size_t)sidx * OUT_DIM))[l4];
            float c = valid ? __expf(ed.y - m) * rd : 0.f;
            a0.x += c * bf2f(uv.x); a0.y += c * bf2f(uv.y);
            a0.z += c * bf2f(uv.z); a0.w += c * bf2f(uv.w);
        }
        a0.x += a1.x; a0.y += a1.y; a0.z += a1.z; a0.w += a1.w;

        #pragma unroll
        for (int off = 32; off >= 16; off >>= 1) {
            a0.x += __shfl_xor(a0.x, off);
            a0.y += __shfl_xor(a0.y, off);
            a0.z += __shfl_xor(a0.z, off);
            a0.w += __shfl_xor(a0.w, off);
        }
        if (g == 0)
            ((float4*)(out + (size_t)node * OUT_DIM))[l4] = a0;
    }
}

extern "C" void kernel_launch(void* const* d_in, const int* in_sizes, int n_in,
                              void* d_out, int out_size, void* d_ws, size_t ws_size,
                              hipStream_t stream) {
    const float* x     = (const float*)d_in[0];
    const int*   eidx  = (const int*)d_in[1];
    const float* ew    = (const float*)d_in[2];
    const float* W     = (const float*)d_in[3];
    const float* a_src = (const float*)d_in[4];
    const float* a_tgt = (const float*)d_in[5];
    float* out = (float*)d_out;

    const int n = in_sizes[0] / IN_DIM;     // 100000
    const int E = in_sizes[2];              // 3200000
    const int* src = eidx;
    const int* tgt = eidx + E;
    const int nbkt = (n + BKN - 1) / BKN;        // 391 <= MAXBKT
    const int nsb  = (E + SCHUNK - 1) / SCHUNK;  // 391 <= 512

    // Workspace layout (4-byte units).
    // hh 12.8 + hs/ht 0.8 + bfill + histT 0.61 + windows 28.8 ~= 43.1 MB.
    unsigned* ws = (unsigned*)d_ws;
    unsigned short* hh = (unsigned short*)ws;  ws += (size_t)n * OUT_DIM / 2;
    float* hs     = (float*)ws;          ws += n;
    float* ht     = (float*)ws;          ws += n;
    int*   bfill  = (int*)ws;            ws += MAXBKT;
    int*   histT  = (int*)ws;            ws += (size_t)nbkt * nsb;
    ws = (unsigned*)(((uintptr_t)ws + 7) & ~(uintptr_t)7);
    float2* ecoarse = (float2*)ws;       // nbkt * CAP records (fixed windows)

    k_linear<<<(n + 63) / 64, 256, 0, stream>>>(x, W, a_src, a_tgt, hh, hs, ht, n);
    k_count<<<nsb, 1024, 0, stream>>>(tgt, histT, E, nbkt, nsb);
    k_colscan<<<nbkt, 512, 0, stream>>>(histT, bfill, nsb);
    k_scat<<<nsb, 1024, 0, stream>>>(src, tgt, ew, hs, ht, histT, ecoarse, E, nbkt, nsb);
    k_bucket<<<nbkt, 1024, 0, stream>>>(bfill, ecoarse, hh, out, n);
}